// Round 17
// baseline (278.285 us; speedup 1.0000x reference)
//
#include <hip/hip_runtime.h>
#include <math.h>

#define IMG 512
#define IMG2 (IMG * IMG)
#define NPIX (64 * IMG2)
#define ZPB 8  // images per block; grid z = 8 -> 2048 blocks, 5 resident/CU (32KB LDS)

// g_c: packed f16 coefficient tables (written by sum_target block 0, read by main)
// [0..6]   cE01=pk(E0,E1) [7..13] cE23=pk(E2,E3) [14..20] cV01 [21..27] cV2
// [28..34] d2=pk(E1,E2)   [35..41] d3=pk(E2,-V2) [42..48] d4=pk(-V0,-V1) [49..55] d5=pk(E3,0)
// [56..58] invS4  [59..61] invN2
__device__ float g_c[64];

typedef __fp16 h2_t __attribute__((ext_vector_type(2)));

__device__ __forceinline__ float rdfl(float x) {
    return __uint_as_float(__builtin_amdgcn_readfirstlane(__float_as_uint(x)));
}
__device__ __forceinline__ unsigned int rdflu(float x) {
    return __builtin_amdgcn_readfirstlane(__float_as_uint(x));
}
__device__ __forceinline__ unsigned int as_u(h2_t h) {
    union { h2_t h; unsigned int u; } c;
    c.h = h;
    return c.u;
}
__device__ __forceinline__ h2_t as_h2(unsigned int u) {
    union { unsigned int u; h2_t h; } c;
    c.u = u;
    return c.h;
}
__device__ __forceinline__ h2_t h2z() {
    h2_t z = {(__fp16)0.f, (__fp16)0.f};
    return z;
}
__device__ __forceinline__ h2_t hmax2(h2_t a, h2_t b) {
    return __builtin_elementwise_max(a, b);
}

__device__ void compute_coeffs() {
    const double step = 7.0 / 6.0;
    float x[7];
    for (int j = 0; j < 7; j++) x[j] = (float)(-4.0 + j * step);
    x[6] = 3.0f;
    const float sigs[4] = {0.5f, 1.0f, 2.0f, 4.0f};
    float E[4][7], Q[4][7], Vv[3][7];
    for (int s = 0; s < 4; s++) {
        float inv = 1.0f / (2.0f * sigs[s] * sigs[s]);
        for (int j = 0; j < 7; j++) {
            float q = x[j] * x[j] * inv;
            Q[s][j] = q;
            E[s][j] = expf(-q);
        }
    }
    for (int s = 0; s < 3; s++)
        for (int j = 0; j < 7; j++) Vv[s][j] = Q[s + 1][j] * E[s + 1][j];

    auto pk2 = [](float a, float b) -> float {
        h2_t h;
        h[0] = (__fp16)a;
        h[1] = (__fp16)b;
        union { h2_t h; float f; } c;
        c.h = h;
        return c.f;
    };
    for (int k = 0; k < 7; k++) {
        g_c[k] = pk2(E[0][k], E[1][k]);
        g_c[7 + k] = pk2(E[2][k], E[3][k]);
        g_c[14 + k] = pk2(Vv[0][k], Vv[1][k]);
        g_c[21 + k] = pk2(Vv[2][k], Vv[2][k]);
        g_c[28 + k] = pk2(E[1][k], E[2][k]);
        g_c[35 + k] = pk2(E[2][k], -Vv[2][k]);
        g_c[42 + k] = pk2(-Vv[0][k], -Vv[1][k]);
        g_c[49 + k] = pk2(E[3][k], 0.f);
    }
    for (int s = 0; s < 3; s++) {
        float gs = 0.f;
        for (int i = 0; i < 7; i++)
            for (int j = 0; j < 7; j++) gs += E[s][i] * E[s][j];
        g_c[56 + s] = 1.0f / (gs * gs);
    }
    for (int s = 1; s < 4; s++) {
        float n = 0.f;
        for (int i = 0; i < 7; i++)
            for (int j = 0; j < 7; j++) {
                float v = E[s][i] * E[s][j] * (1.0f - Q[s][i] - Q[s][j]);
                n += fabsf(v);
            }
        g_c[59 + (s - 1)] = 1.0f / (n * n);
    }
}

// 256 blocks: per-block partial sums of T -> ws[0..255]; block 0 also computes coeffs
__global__ __launch_bounds__(256) void sum_target_kernel(const float4* __restrict__ t4,
                                                          float* __restrict__ ws) {
    if (blockIdx.x == 0 && threadIdx.x == 0) compute_coeffs();
    float s = 0.f;
    for (int i = blockIdx.x * 256 + threadIdx.x; i < NPIX / 4; i += 256 * 256) {
        float4 v = t4[i];
        s += (v.x + v.y) + (v.z + v.w);
    }
    for (int off = 32; off > 0; off >>= 1) s += __shfl_down(s, off);
    __shared__ float ps[4];
    int lane = threadIdx.x & 63, wid = threadIdx.x >> 6;
    if (lane == 0) ps[wid] = s;
    __syncthreads();
    if (threadIdx.x == 0) ws[blockIdx.x] = (ps[0] + ps[1]) + (ps[2] + ps[3]);
}

__global__ __launch_bounds__(256, 5) void main_kernel(const float* __restrict__ R,
                                                      const float* __restrict__ T,
                                                      float* __restrict__ ws) {
    __shared__ float sd[38][44];      // d = r-t f32; pixel px <-> col jj = px+4
    __shared__ unsigned srt[34][44];  // packed f16 (r,t); row = pixelrow+1, col jj = px+4
    __shared__ uint4 hrec[32][39];    // [x][y] h record {he0,he1|he2,he3|tm0,tm1|tm2,tm2}
    __shared__ float red[4];

    const int tid = threadIdx.x;
    const int gx0 = blockIdx.x * 32, gy0 = blockIdx.y * 32;
    const int z0 = blockIdx.z * ZPB;
    const int bid = blockIdx.x + (blockIdx.y << 4) + (blockIdx.z << 8);

    // ---- per-thread load geometry (z-independent) ----
    const int q0 = tid, q1 = tid + 256;
    const bool has1 = (q1 < 380);
    const int i0 = q0 / 10, c0 = q0 - 10 * i0;
    const int i1 = q1 / 10, c1 = q1 - 10 * i1;
    const int gy_0 = gy0 + i0 - 3, gxb0 = gx0 - 4 + 4 * c0;
    const int gy_1 = gy0 + i1 - 3, gxb1 = gx0 - 4 + 4 * c1;
    const int o0 = min(max(gy_0, 0), IMG - 1) * IMG + min(max(gxb0, 0), IMG - 4);
    const int o1 = min(max(gy_1, 0), IMG - 1) * IMG + min(max(gxb1, 0), IMG - 4);
    const bool vy0 = ((unsigned)gy_0 < IMG), vy1 = ((unsigned)gy_1 < IMG);
    bool m0[4], m1[4];
#pragma unroll
    for (int e = 0; e < 4; e++) {
        m0[e] = vy0 && ((unsigned)(gxb0 + e) < IMG);
        m1[e] = vy1 && ((unsigned)(gxb1 + e) < IMG);
    }

    // two prefetch register sets (2-deep z pipeline)
    float4 raA, taA, rbA, tbA;
    float4 raB, taB, rbB, tbB;

#define LOAD_T(zz, S)                          \
    {                                          \
        const float* Rz = R + (long)(zz)*IMG2; \
        const float* Tz = T + (long)(zz)*IMG2; \
        ra##S = *(const float4*)(Rz + o0);     \
        ta##S = *(const float4*)(Tz + o0);     \
        if (has1) {                            \
            rb##S = *(const float4*)(Rz + o1); \
            tb##S = *(const float4*)(Tz + o1); \
        }                                      \
    }

#define WRITE_T(S)                                                                   \
    {                                                                                \
        float rv[4] = {ra##S.x, ra##S.y, ra##S.z, ra##S.w};                          \
        float tv[4] = {ta##S.x, ta##S.y, ta##S.z, ta##S.w};                          \
        float dq[4];                                                                 \
        unsigned pkq[4];                                                             \
        _Pragma("unroll") for (int e = 0; e < 4; e++) {                              \
            dq[e] = m0[e] ? (rv[e] - tv[e]) : 0.f;                                   \
            h2_t h = __builtin_amdgcn_cvt_pkrtz(rv[e], tv[e]);                       \
            pkq[e] = m0[e] ? as_u(h) : 0xFC00FC00u;                                  \
        }                                                                            \
        *(float4*)&sd[i0][4 * c0] = make_float4(dq[0], dq[1], dq[2], dq[3]);         \
        if (i0 >= 2 && i0 < 36)                                                      \
            *(uint4*)&srt[i0 - 2][4 * c0] = make_uint4(pkq[0], pkq[1], pkq[2], pkq[3]); \
        if (has1) {                                                                  \
            float rv1[4] = {rb##S.x, rb##S.y, rb##S.z, rb##S.w};                     \
            float tv1[4] = {tb##S.x, tb##S.y, tb##S.z, tb##S.w};                     \
            float dq1[4];                                                            \
            unsigned pkq1[4];                                                        \
            _Pragma("unroll") for (int e = 0; e < 4; e++) {                          \
                dq1[e] = m1[e] ? (rv1[e] - tv1[e]) : 0.f;                            \
                h2_t h = __builtin_amdgcn_cvt_pkrtz(rv1[e], tv1[e]);                 \
                pkq1[e] = m1[e] ? as_u(h) : 0xFC00FC00u;                             \
            }                                                                        \
            *(float4*)&sd[i1][4 * c1] = make_float4(dq1[0], dq1[1], dq1[2], dq1[3]); \
            if (i1 >= 2 && i1 < 36)                                                  \
                *(uint4*)&srt[i1 - 2][4 * c1] =                                      \
                    make_uint4(pkq1[0], pkq1[1], pkq1[2], pkq1[3]);                  \
        }                                                                            \
    }

// phases as macros: textual inlining, no lambda capture (round-16 spill lesson)
#define PHASE2()                                                                     \
    {                                                                                \
        float dw[6][3];                                                              \
        _Pragma("unroll") for (int r = 0; r < 6; r++)                                \
            _Pragma("unroll") for (int c = 0; c < 3; c++)                            \
                dw[r][c] = sd[y0 + 2 + r][x + 3 + c];                                \
        float rxx[6], rss[6];                                                        \
        _Pragma("unroll") for (int r = 0; r < 6; r++) {                              \
            rxx[r] = dw[r][2] - dw[r][0];                                            \
            rss[r] = dw[r][0] + 2.f * dw[r][1] + dw[r][2];                           \
        }                                                                            \
        h2_t cm[6];                                                                  \
        float tcv[6];                                                                \
        _Pragma("unroll") for (int r = 0; r < 6; r++) {                              \
            h2_t a = as_h2(srt[y0 + r][x + 3]);                                      \
            h2_t b = as_h2(srt[y0 + r][x + 4]);                                      \
            h2_t c = as_h2(srt[y0 + r][x + 5]);                                      \
            cm[r] = hmax2(hmax2(a, b), c);                                           \
            tcv[r] = (float)b[1];                                                    \
        }                                                                            \
        _Pragma("unroll") for (int yy = 0; yy < 4; yy++) {                           \
            float sx = rxx[yy] + 2.f * rxx[yy + 1] + rxx[yy + 2];                    \
            float sy = rss[yy + 2] - rss[yy];                                        \
            float pt = 4.f * dw[yy + 1][1] - dw[yy][1] - dw[yy + 2][1] -             \
                       dw[yy + 1][0] - dw[yy + 1][2];                                \
            float d = dw[yy + 1][1];                                                 \
            float w2 = (tcv[yy + 1] > mean) ? 9.f : 1.f;                             \
            h2_t wm = hmax2(hmax2(cm[yy], cm[yy + 1]), cm[yy + 2]);                  \
            float mr = (float)wm[0], mt = (float)wm[1];                              \
            total += w2 * d * d + 2.f * (sx * sx + sy * sy) + 1.5f * pt * pt +       \
                     2.f * fabsf(mr - mt);                                           \
        }                                                                            \
    }

#define PHASE3()                                                                     \
    for (int j = tid; j < 304; j += 256) {                                           \
        int xq = j / 38, y = j - 38 * xq;                                            \
        const float* rp = &sd[y][4 * xq];                                            \
        float4 A = *(const float4*)(rp);                                             \
        float4 B = *(const float4*)(rp + 4);                                         \
        float4 C = *(const float4*)(rp + 8);                                         \
        float w[12] = {A.x, A.y, A.z, A.w, B.x, B.y, B.z, B.w, C.x, C.y, C.z, C.w};  \
        h2_t wp[12];                                                                 \
        _Pragma("unroll") for (int i = 0; i < 12; i++)                               \
            wp[i] = __builtin_amdgcn_cvt_pkrtz(w[i], w[i]);                          \
        _Pragma("unroll") for (int p = 0; p < 4; p++) {                              \
            h2_t aE01 = h2z(), aE23 = h2z(), aV01 = h2z(), aV2 = h2z();              \
            _Pragma("unroll") for (int k = 0; k < 7; k++) {                          \
                h2_t d = wp[p + 1 + k];                                              \
                aE01 = cE01[k] * d + aE01;                                           \
                aE23 = cE23[k] * d + aE23;                                           \
                aV01 = cV01[k] * d + aV01;                                           \
                aV2 = cV2[k] * d + aV2;                                              \
            }                                                                        \
            h2_t he12 = __builtin_shufflevector(aE01, aE23, 1, 2);                   \
            h2_t tm01 = he12 - aV01;                                                 \
            h2_t he33 = __builtin_shufflevector(aE23, aE23, 1, 1);                   \
            h2_t tm22 = he33 - aV2;                                                  \
            hrec[4 * xq + p][y] =                                                    \
                make_uint4(as_u(aE01), as_u(aE23), as_u(tm01), as_u(tm22));          \
        }                                                                            \
    }

#define PHASE4()                                                                     \
    {                                                                                \
        h2_t A1[4], A2[4], A3[4], A4[4], A5[4];                                      \
        _Pragma("unroll") for (int yy = 0; yy < 4; yy++) {                           \
            A1[yy] = h2z();                                                          \
            A2[yy] = h2z();                                                          \
            A3[yy] = h2z();                                                          \
            A4[yy] = h2z();                                                          \
            A5[yy] = h2z();                                                          \
        }                                                                            \
        _Pragma("unroll") for (int q = 0; q < 10; q++) {                             \
            uint4 rec = hrec[x][y0 + q];                                             \
            h2_t rx = as_h2(rec.x), ry = as_h2(rec.y);                               \
            h2_t rz = as_h2(rec.z), rw = as_h2(rec.w);                               \
            h2_t r12 = __builtin_shufflevector(rx, ry, 1, 2);                        \
            _Pragma("unroll") for (int yy = 0; yy < 4; yy++) {                       \
                const int k = q - yy;                                                \
                if (k >= 0 && k <= 6) {                                              \
                    A1[yy] = cE01[k] * rx + A1[yy];                                  \
                    A2[yy] = d2c[k] * rz + A2[yy];                                   \
                    A3[yy] = d3c[k] * ry + A3[yy];                                   \
                    A4[yy] = d4c[k] * r12 + A4[yy];                                  \
                    A5[yy] = d5c[k] * rw + A5[yy];                                   \
                }                                                                    \
            }                                                                        \
        }                                                                            \
        _Pragma("unroll") for (int yy = 0; yy < 4; yy++) {                           \
            h2_t Bp = A2[yy] + A4[yy];                                               \
            float g0 = (float)A1[yy][0], g1 = (float)A1[yy][1];                      \
            float g2 = (float)A3[yy][0];                                             \
            float aL0 = (float)Bp[0], aL1 = (float)Bp[1];                            \
            float aL2 = (float)A5[yy][0] + (float)A3[yy][1];                         \
            total += invS4[0] * g0 * g0 + invS4[1] * g1 * g1 + invS4[2] * g2 * g2 +  \
                     invN2[0] * aL0 * aL0 + invN2[1] * aL1 * aL1 +                   \
                     invN2[2] * aL2 * aL2;                                           \
        }                                                                            \
    }

    // issue first tile's loads ASAP; mean-reduce + coeff loads overlap the latency
    LOAD_T(z0, A);

    // ---- mean of T from the 256 partials ----
    {
        float v = ws[tid];
        for (int off = 32; off > 0; off >>= 1) v += __shfl_down(v, off);
        int lane = tid & 63, wid = tid >> 6;
        if (lane == 0) red[wid] = v;
        __syncthreads();
    }
    const float mean = rdfl(((red[0] + red[1]) + (red[2] + red[3])) * (1.0f / (float)NPIX));

    // packed coefficients -> SGPR uints
    h2_t cE01[7], cE23[7], cV01[7], cV2[7], d2c[7], d3c[7], d4c[7], d5c[7];
#pragma unroll
    for (int k = 0; k < 7; k++) {
        cE01[k] = as_h2(rdflu(g_c[k]));
        cE23[k] = as_h2(rdflu(g_c[7 + k]));
        cV01[k] = as_h2(rdflu(g_c[14 + k]));
        cV2[k] = as_h2(rdflu(g_c[21 + k]));
        d2c[k] = as_h2(rdflu(g_c[28 + k]));
        d3c[k] = as_h2(rdflu(g_c[35 + k]));
        d4c[k] = as_h2(rdflu(g_c[42 + k]));
        d5c[k] = as_h2(rdflu(g_c[49 + k]));
    }
    float invS4[3], invN2[3];
#pragma unroll
    for (int s = 0; s < 3; s++) {
        invS4[s] = rdfl(g_c[56 + s]);
        invN2[s] = rdfl(g_c[59 + s]);
    }

    const int x = tid & 31;
    const int y0 = (tid >> 5) * 4;

    float total = 0.f;

    // ---- prologue: tile0 staged; tile1 loads in flight ----
    WRITE_T(A);
    LOAD_T(z0 + 1, A);  // A free after its WRITE; now holds tile 1
    __syncthreads();

    // ---- 2-deep pipelined z loop (even: load->B, write<-A; odd: load->A, write<-B) ----
    for (int itp = 0; itp < ZPB; itp += 2) {
        // iteration itp (even)
        if (itp + 2 < ZPB) LOAD_T(z0 + itp + 2, B);
        PHASE2();
        PHASE3();
        __syncthreads();  // S1: sd/srt reads + hrec writes complete
        if (itp + 1 < ZPB) WRITE_T(A);
        PHASE4();
        __syncthreads();  // S2: next-tile LDS writes visible; hrec reads done

        // iteration itp+1 (odd)
        if (itp + 3 < ZPB) LOAD_T(z0 + itp + 3, A);
        PHASE2();
        PHASE3();
        __syncthreads();  // S1
        if (itp + 2 < ZPB) WRITE_T(B);
        PHASE4();
        __syncthreads();  // S2
    }

    // ---- block reduction -> per-block partial (plain store, no atomics) ----
    for (int off = 32; off > 0; off >>= 1) total += __shfl_down(total, off);
    int lane = tid & 63, wid = tid >> 6;
    if (lane == 0) red[wid] = total;
    __syncthreads();
    if (tid == 0) ws[256 + bid] = (red[0] + red[1]) + (red[2] + red[3]);
}

__global__ __launch_bounds__(256) void finalize_kernel(const float* __restrict__ ws,
                                                       float* __restrict__ out) {
    float s = 0.f;
    for (int i = threadIdx.x; i < 2048; i += 256) s += ws[256 + i];
    for (int off = 32; off > 0; off >>= 1) s += __shfl_down(s, off);
    __shared__ float ps[4];
    int lane = threadIdx.x & 63, wid = threadIdx.x >> 6;
    if (lane == 0) ps[wid] = s;
    __syncthreads();
    if (threadIdx.x == 0)
        out[0] = ((ps[0] + ps[1]) + (ps[2] + ps[3])) * (1.0f / (float)NPIX);
}

extern "C" void kernel_launch(void* const* d_in, const int* in_sizes, int n_in,
                              void* d_out, int out_size, void* d_ws, size_t ws_size,
                              hipStream_t stream) {
    const float* recon = (const float*)d_in[0];
    const float* target = (const float*)d_in[1];
    float* ws = (float*)d_ws;  // [0..255] T partials, [256..2303] loss partials

    hipLaunchKernelGGL(sum_target_kernel, dim3(256), dim3(256), 0, stream,
                       (const float4*)target, ws);
    dim3 grid(16, 16, 64 / ZPB), block(256);
    hipLaunchKernelGGL(main_kernel, grid, block, 0, stream, recon, target, ws);
    hipLaunchKernelGGL(finalize_kernel, dim3(1), dim3(256), 0, stream, ws, (float*)d_out);
}

// Round 18
// 107.788 us; speedup vs baseline: 2.5818x; 2.5818x over previous
//
#include <hip/hip_runtime.h>
#include <math.h>

#define IMG 512
#define IMG2 (IMG * IMG)
#define NPIX (64 * IMG2)
#define ZPB 8  // images per block; grid z = 8 -> 2048 blocks, ~5 resident/CU (32KB LDS)

// g_c: packed f16 coefficient tables (written by sum_target block 0, read by main)
// [0..6]   cE01=pk(E0,E1) [7..13] cE23=pk(E2,E3) [14..20] cV01 [21..27] cV2
// [28..34] d2=pk(E1,E2)   [35..41] d3=pk(E2,-V2) [42..48] d4=pk(-V0,-V1) [49..55] d5=pk(E3,0)
// [56..58] invS4  [59..61] invN2
__device__ float g_c[64];

typedef __fp16 h2_t __attribute__((ext_vector_type(2)));

__device__ __forceinline__ float rdfl(float x) {
    return __uint_as_float(__builtin_amdgcn_readfirstlane(__float_as_uint(x)));
}
__device__ __forceinline__ unsigned int rdflu(float x) {
    return __builtin_amdgcn_readfirstlane(__float_as_uint(x));
}
__device__ __forceinline__ unsigned int as_u(h2_t h) {
    union { h2_t h; unsigned int u; } c;
    c.h = h;
    return c.u;
}
__device__ __forceinline__ h2_t as_h2(unsigned int u) {
    union { unsigned int u; h2_t h; } c;
    c.u = u;
    return c.h;
}
__device__ __forceinline__ h2_t h2z() {
    h2_t z = {(__fp16)0.f, (__fp16)0.f};
    return z;
}
__device__ __forceinline__ h2_t hmax2(h2_t a, h2_t b) {
    return __builtin_elementwise_max(a, b);
}

__device__ void compute_coeffs() {
    const double step = 7.0 / 6.0;
    float x[7];
    for (int j = 0; j < 7; j++) x[j] = (float)(-4.0 + j * step);
    x[6] = 3.0f;
    const float sigs[4] = {0.5f, 1.0f, 2.0f, 4.0f};
    float E[4][7], Q[4][7], Vv[3][7];
    for (int s = 0; s < 4; s++) {
        float inv = 1.0f / (2.0f * sigs[s] * sigs[s]);
        for (int j = 0; j < 7; j++) {
            float q = x[j] * x[j] * inv;
            Q[s][j] = q;
            E[s][j] = expf(-q);
        }
    }
    for (int s = 0; s < 3; s++)
        for (int j = 0; j < 7; j++) Vv[s][j] = Q[s + 1][j] * E[s + 1][j];

    auto pk2 = [](float a, float b) -> float {
        h2_t h;
        h[0] = (__fp16)a;
        h[1] = (__fp16)b;
        union { h2_t h; float f; } c;
        c.h = h;
        return c.f;
    };
    for (int k = 0; k < 7; k++) {
        g_c[k] = pk2(E[0][k], E[1][k]);
        g_c[7 + k] = pk2(E[2][k], E[3][k]);
        g_c[14 + k] = pk2(Vv[0][k], Vv[1][k]);
        g_c[21 + k] = pk2(Vv[2][k], Vv[2][k]);
        g_c[28 + k] = pk2(E[1][k], E[2][k]);
        g_c[35 + k] = pk2(E[2][k], -Vv[2][k]);
        g_c[42 + k] = pk2(-Vv[0][k], -Vv[1][k]);
        g_c[49 + k] = pk2(E[3][k], 0.f);
    }
    for (int s = 0; s < 3; s++) {
        float gs = 0.f;
        for (int i = 0; i < 7; i++)
            for (int j = 0; j < 7; j++) gs += E[s][i] * E[s][j];
        g_c[56 + s] = 1.0f / (gs * gs);
    }
    for (int s = 1; s < 4; s++) {
        float n = 0.f;
        for (int i = 0; i < 7; i++)
            for (int j = 0; j < 7; j++) {
                float v = E[s][i] * E[s][j] * (1.0f - Q[s][i] - Q[s][j]);
                n += fabsf(v);
            }
        g_c[59 + (s - 1)] = 1.0f / (n * n);
    }
}

// 256 blocks: per-block partial sums of T -> ws[0..255]; block 0 also computes coeffs
__global__ __launch_bounds__(256) void sum_target_kernel(const float4* __restrict__ t4,
                                                          float* __restrict__ ws) {
    if (blockIdx.x == 0 && threadIdx.x == 0) compute_coeffs();
    float s = 0.f;
    for (int i = blockIdx.x * 256 + threadIdx.x; i < NPIX / 4; i += 256 * 256) {
        float4 v = t4[i];
        s += (v.x + v.y) + (v.z + v.w);
    }
    for (int off = 32; off > 0; off >>= 1) s += __shfl_down(s, off);
    __shared__ float ps[4];
    int lane = threadIdx.x & 63, wid = threadIdx.x >> 6;
    if (lane == 0) ps[wid] = s;
    __syncthreads();
    if (threadIdx.x == 0) ws[blockIdx.x] = (ps[0] + ps[1]) + (ps[2] + ps[3]);
}

__global__ __launch_bounds__(256, 5) void main_kernel(const float* __restrict__ R,
                                                      const float* __restrict__ T,
                                                      float* __restrict__ ws) {
    __shared__ float sd[38][44];      // d = r-t f32; pixel px <-> col jj = px+4
    __shared__ unsigned srt[34][44];  // packed f16 (r,t); row = pixelrow+1, col jj = px+4
    __shared__ uint4 hrec[32][39];    // [x][y] h record {he0,he1|he2,he3|tm0,tm1|tm2,tm2}
    __shared__ float red[4];

    const int tid = threadIdx.x;
    const int gx0 = blockIdx.x * 32, gy0 = blockIdx.y * 32;
    const int z0 = blockIdx.z * ZPB;
    const int bid = blockIdx.x + (blockIdx.y << 4) + (blockIdx.z << 8);

    // ---- mean of T from the 256 partials ----
    {
        float v = ws[tid];
        for (int off = 32; off > 0; off >>= 1) v += __shfl_down(v, off);
        int lane = tid & 63, wid = tid >> 6;
        if (lane == 0) red[wid] = v;
        __syncthreads();
    }
    const float mean = rdfl(((red[0] + red[1]) + (red[2] + red[3])) * (1.0f / (float)NPIX));

    // packed coefficients -> SGPR uints
    h2_t cE01[7], cE23[7], cV01[7], cV2[7], d2c[7], d3c[7], d4c[7], d5c[7];
#pragma unroll
    for (int k = 0; k < 7; k++) {
        cE01[k] = as_h2(rdflu(g_c[k]));
        cE23[k] = as_h2(rdflu(g_c[7 + k]));
        cV01[k] = as_h2(rdflu(g_c[14 + k]));
        cV2[k] = as_h2(rdflu(g_c[21 + k]));
        d2c[k] = as_h2(rdflu(g_c[28 + k]));
        d3c[k] = as_h2(rdflu(g_c[35 + k]));
        d4c[k] = as_h2(rdflu(g_c[42 + k]));
        d5c[k] = as_h2(rdflu(g_c[49 + k]));
    }
    float invS4[3], invN2[3];
#pragma unroll
    for (int s = 0; s < 3; s++) {
        invS4[s] = rdfl(g_c[56 + s]);
        invN2[s] = rdfl(g_c[59 + s]);
    }

    // ---- per-thread load geometry (z-independent) ----
    const int q0 = tid, q1 = tid + 256;
    const bool has1 = (q1 < 380);
    const int i0 = q0 / 10, c0 = q0 - 10 * i0;
    const int i1 = q1 / 10, c1 = q1 - 10 * i1;
    const int gy_0 = gy0 + i0 - 3, gxb0 = gx0 - 4 + 4 * c0;
    const int gy_1 = gy0 + i1 - 3, gxb1 = gx0 - 4 + 4 * c1;
    const int o0 = min(max(gy_0, 0), IMG - 1) * IMG + min(max(gxb0, 0), IMG - 4);
    const int o1 = min(max(gy_1, 0), IMG - 1) * IMG + min(max(gxb1, 0), IMG - 4);
    const bool vy0 = ((unsigned)gy_0 < IMG), vy1 = ((unsigned)gy_1 < IMG);
    bool m0[4], m1[4];
#pragma unroll
    for (int e = 0; e < 4; e++) {
        m0[e] = vy0 && ((unsigned)(gxb0 + e) < IMG);
        m1[e] = vy1 && ((unsigned)(gxb1 + e) < IMG);
    }

    const int x = tid & 31;
    const int y0 = (tid >> 5) * 4;

    float4 ra, ta, rb, tb;  // prefetch registers

#define LOAD_TILE(zz)                          \
    {                                          \
        const float* Rz = R + (long)(zz)*IMG2; \
        const float* Tz = T + (long)(zz)*IMG2; \
        ra = *(const float4*)(Rz + o0);        \
        ta = *(const float4*)(Tz + o0);        \
        if (has1) {                            \
            rb = *(const float4*)(Rz + o1);    \
            tb = *(const float4*)(Tz + o1);    \
        }                                      \
    }

#define WRITE_TILE()                                                                 \
    {                                                                                \
        float rv[4] = {ra.x, ra.y, ra.z, ra.w};                                      \
        float tv[4] = {ta.x, ta.y, ta.z, ta.w};                                      \
        float dq[4];                                                                 \
        unsigned pkq[4];                                                             \
        _Pragma("unroll") for (int e = 0; e < 4; e++) {                              \
            dq[e] = m0[e] ? (rv[e] - tv[e]) : 0.f;                                   \
            h2_t h = __builtin_amdgcn_cvt_pkrtz(rv[e], tv[e]);                       \
            pkq[e] = m0[e] ? as_u(h) : 0xFC00FC00u;                                  \
        }                                                                            \
        *(float4*)&sd[i0][4 * c0] = make_float4(dq[0], dq[1], dq[2], dq[3]);         \
        if (i0 >= 2 && i0 < 36)                                                      \
            *(uint4*)&srt[i0 - 2][4 * c0] = make_uint4(pkq[0], pkq[1], pkq[2], pkq[3]); \
        if (has1) {                                                                  \
            float rv1[4] = {rb.x, rb.y, rb.z, rb.w};                                 \
            float tv1[4] = {tb.x, tb.y, tb.z, tb.w};                                 \
            float dq1[4];                                                            \
            unsigned pkq1[4];                                                        \
            _Pragma("unroll") for (int e = 0; e < 4; e++) {                          \
                dq1[e] = m1[e] ? (rv1[e] - tv1[e]) : 0.f;                            \
                h2_t h = __builtin_amdgcn_cvt_pkrtz(rv1[e], tv1[e]);                 \
                pkq1[e] = m1[e] ? as_u(h) : 0xFC00FC00u;                             \
            }                                                                        \
            *(float4*)&sd[i1][4 * c1] = make_float4(dq1[0], dq1[1], dq1[2], dq1[3]); \
            if (i1 >= 2 && i1 < 36)                                                  \
                *(uint4*)&srt[i1 - 2][4 * c1] =                                      \
                    make_uint4(pkq1[0], pkq1[1], pkq1[2], pkq1[3]);                  \
        }                                                                            \
    }

    LOAD_TILE(z0);
    WRITE_TILE();
    __syncthreads();

    float total = 0.f;

    for (int it = 0; it < ZPB; ++it) {
        const bool havenext = (it + 1 < ZPB);
        if (havenext) LOAD_TILE(z0 + it + 1);  // issue early; consumed after S1

        // ---- phase 2: local terms; column-per-thread scalar reads (conflict-free) ----
        {
            float dw[6][3];
#pragma unroll
            for (int r = 0; r < 6; r++)
#pragma unroll
                for (int c = 0; c < 3; c++) dw[r][c] = sd[y0 + 2 + r][x + 3 + c];
            float rx[6], rs[6];
#pragma unroll
            for (int r = 0; r < 6; r++) {
                rx[r] = dw[r][2] - dw[r][0];
                rs[r] = dw[r][0] + 2.f * dw[r][1] + dw[r][2];
            }
            h2_t cm[6];
            float tc[6];
#pragma unroll
            for (int r = 0; r < 6; r++) {
                h2_t a = as_h2(srt[y0 + r][x + 3]);
                h2_t b = as_h2(srt[y0 + r][x + 4]);
                h2_t c = as_h2(srt[y0 + r][x + 5]);
                cm[r] = hmax2(hmax2(a, b), c);
                tc[r] = (float)b[1];
            }
#pragma unroll
            for (int yy = 0; yy < 4; yy++) {
                float sx = rx[yy] + 2.f * rx[yy + 1] + rx[yy + 2];
                float sy = rs[yy + 2] - rs[yy];
                float pt = 4.f * dw[yy + 1][1] - dw[yy][1] - dw[yy + 2][1] - dw[yy + 1][0] -
                           dw[yy + 1][2];
                float d = dw[yy + 1][1];
                float w2 = (tc[yy + 1] > mean) ? 9.f : 1.f;
                h2_t wm = hmax2(hmax2(cm[yy], cm[yy + 1]), cm[yy + 2]);
                float mr = (float)wm[0], mt = (float)wm[1];
                total += w2 * d * d + 2.f * (sx * sx + sy * sy) + 1.5f * pt * pt +
                         2.f * fabsf(mr - mt);
            }
        }

        // ---- phase 3: horizontal pass (packed f16), job = (xq, y), y fastest ----
        for (int j = tid; j < 304; j += 256) {
            int xq = j / 38, y = j - 38 * xq;  // xq 0..7, y 0..37
            const float* rp = &sd[y][4 * xq];
            float4 A = *(const float4*)(rp);
            float4 B = *(const float4*)(rp + 4);
            float4 C = *(const float4*)(rp + 8);
            float w[12] = {A.x, A.y, A.z, A.w, B.x, B.y, B.z, B.w, C.x, C.y, C.z, C.w};
            h2_t wp[12];
#pragma unroll
            for (int i = 0; i < 12; i++) wp[i] = __builtin_amdgcn_cvt_pkrtz(w[i], w[i]);
#pragma unroll
            for (int p = 0; p < 4; p++) {
                h2_t aE01 = h2z(), aE23 = h2z(), aV01 = h2z(), aV2 = h2z();
#pragma unroll
                for (int k = 0; k < 7; k++) {
                    h2_t d = wp[p + 1 + k];
                    aE01 = cE01[k] * d + aE01;
                    aE23 = cE23[k] * d + aE23;
                    aV01 = cV01[k] * d + aV01;
                    aV2 = cV2[k] * d + aV2;
                }
                h2_t he12 = __builtin_shufflevector(aE01, aE23, 1, 2);  // (he1,he2)
                h2_t tm01 = he12 - aV01;                                // (tm0,tm1)
                h2_t he33 = __builtin_shufflevector(aE23, aE23, 1, 1);  // (he3,he3)
                h2_t tm22 = he33 - aV2;                                 // (tm2,tm2)
                hrec[4 * xq + p][y] =
                    make_uint4(as_u(aE01), as_u(aE23), as_u(tm01), as_u(tm22));
            }
        }
        __syncthreads();  // S1: sd/srt reads + hrec writes complete

        if (havenext) WRITE_TILE();  // stage next tile (disjoint from hrec)

        // ---- phase 4: vertical pass (packed f16), rolling over 10 h-rows ----
        {
            h2_t A1[4], A2[4], A3[4], A4[4], A5[4];
#pragma unroll
            for (int yy = 0; yy < 4; yy++) {
                A1[yy] = h2z();
                A2[yy] = h2z();
                A3[yy] = h2z();
                A4[yy] = h2z();
                A5[yy] = h2z();
            }
#pragma unroll
            for (int q = 0; q < 10; q++) {
                uint4 rec = hrec[x][y0 + q];
                h2_t rx = as_h2(rec.x), ry = as_h2(rec.y);
                h2_t rz = as_h2(rec.z), rw = as_h2(rec.w);
                h2_t r12 = __builtin_shufflevector(rx, ry, 1, 2);  // (he1,he2)
#pragma unroll
                for (int yy = 0; yy < 4; yy++) {
                    const int k = q - yy;
                    if (k >= 0 && k <= 6) {
                        A1[yy] = cE01[k] * rx + A1[yy];  // (g0, g1)
                        A2[yy] = d2c[k] * rz + A2[yy];   // (aL0a, aL1a)
                        A3[yy] = d3c[k] * ry + A3[yy];   // (g2, aL2b)
                        A4[yy] = d4c[k] * r12 + A4[yy];  // (aL0b, aL1b)
                        A5[yy] = d5c[k] * rw + A5[yy];   // (aL2a, 0)
                    }
                }
            }
#pragma unroll
            for (int yy = 0; yy < 4; yy++) {
                h2_t Bp = A2[yy] + A4[yy];  // (aL0, aL1)
                float g0 = (float)A1[yy][0], g1 = (float)A1[yy][1];
                float g2 = (float)A3[yy][0];
                float aL0 = (float)Bp[0], aL1 = (float)Bp[1];
                float aL2 = (float)A5[yy][0] + (float)A3[yy][1];
                total += invS4[0] * g0 * g0 + invS4[1] * g1 * g1 + invS4[2] * g2 * g2 +
                         invN2[0] * aL0 * aL0 + invN2[1] * aL1 * aL1 + invN2[2] * aL2 * aL2;
            }
        }
        __syncthreads();  // S2: next-tile LDS writes visible; hrec reads done
    }

    // ---- block reduction -> per-block partial (plain store, no atomics) ----
    for (int off = 32; off > 0; off >>= 1) total += __shfl_down(total, off);
    int lane = tid & 63, wid = tid >> 6;
    if (lane == 0) red[wid] = total;
    __syncthreads();
    if (tid == 0) ws[256 + bid] = (red[0] + red[1]) + (red[2] + red[3]);
}

__global__ __launch_bounds__(256) void finalize_kernel(const float* __restrict__ ws,
                                                       float* __restrict__ out) {
    float s = 0.f;
    for (int i = threadIdx.x; i < 2048; i += 256) s += ws[256 + i];
    for (int off = 32; off > 0; off >>= 1) s += __shfl_down(s, off);
    __shared__ float ps[4];
    int lane = threadIdx.x & 63, wid = threadIdx.x >> 6;
    if (lane == 0) ps[wid] = s;
    __syncthreads();
    if (threadIdx.x == 0)
        out[0] = ((ps[0] + ps[1]) + (ps[2] + ps[3])) * (1.0f / (float)NPIX);
}

extern "C" void kernel_launch(void* const* d_in, const int* in_sizes, int n_in,
                              void* d_out, int out_size, void* d_ws, size_t ws_size,
                              hipStream_t stream) {
    const float* recon = (const float*)d_in[0];
    const float* target = (const float*)d_in[1];
    float* ws = (float*)d_ws;  // [0..255] T partials, [256..2303] loss partials

    hipLaunchKernelGGL(sum_target_kernel, dim3(256), dim3(256), 0, stream,
                       (const float4*)target, ws);
    dim3 grid(16, 16, 64 / ZPB), block(256);
    hipLaunchKernelGGL(main_kernel, grid, block, 0, stream, recon, target, ws);
    hipLaunchKernelGGL(finalize_kernel, dim3(1), dim3(256), 0, stream, ws, (float*)d_out);
}